// Round 7
// baseline (504.484 us; speedup 1.0000x reference)
//
#include <hip/hip_runtime.h>

#define NN 50000
#define NE 800000
#define INDIM 256
#define HIDD 128
#define ODIM 3
#define EDIM 4
#define NLAYERS 4

typedef __attribute__((ext_vector_type(8))) short bf16x8;
typedef __attribute__((ext_vector_type(4))) float f32x4;
typedef __attribute__((ext_vector_type(2))) float f32x2;

// round-to-nearest-even fp32 -> bf16 bits (finite inputs)
__device__ __forceinline__ ushort f2bf(float f) {
    unsigned int x = __float_as_uint(f);
    unsigned int r = (x + 0x7fffu + ((x >> 16) & 1u)) >> 16;
    return (ushort)r;
}
__device__ __forceinline__ float bf2f(ushort u) {
    return __uint_as_float(((unsigned int)u) << 16);
}
__device__ __forceinline__ float lo16f(unsigned int u) {
    return __uint_as_float(u << 16);
}
__device__ __forceinline__ float hi16f(unsigned int u) {
    return __uint_as_float(u & 0xffff0000u);
}

__device__ __forceinline__ bf16x8 loadA8(const ushort* p, bool ok) {
    if (ok) return *(const bf16x8*)p;
    bf16x8 z = {0, 0, 0, 0, 0, 0, 0, 0};
    return z;
}

// XCD-pairing swizzle: grid 400, col-half pair 8 apart (perf-only hint)
__device__ __forceinline__ bool swizzle400(int b, int& x, int& y) {
    x = (b >> 3) & 1;
    y = (b >> 4) * 8 + (b & 7);
    return y < 196;
}

// ---------------------------------------------------------------------------
// Weights-resident MFMA GEMM, bf16 A (x state), 2-term exact-weight split:
//   C = A@Bh + A@Bl (+bias).  B^T [n][k] hi/lo staged to LDS once;
//   barrier-free k-loop; A frags from global (16B/lane coalesced).
// ---------------------------------------------------------------------------
template<int NJ, int KSTEPS>
__global__ __launch_bounds__(512, 4) void gemm_wres(
    const ushort* __restrict__ Ah,
    const ushort* __restrict__ BTh, const ushort* __restrict__ BTl,
    const float* __restrict__ bias,
    ushort* __restrict__ Cb, int M, int lda, int ldc)
{
    constexpr int K  = KSTEPS * 32;
    constexpr int N  = NJ * 16;
    constexpr int KP = K + 8;                 // padded LDS stride (2-way alias = free)
    extern __shared__ ushort sB[];            // [2][N][KP]
    ushort* sBh = sB;
    ushort* sBl = sB + (size_t)N * KP;

    int bx, by;
    if (!swizzle400(blockIdx.x, bx, by)) return;

    const int tid     = threadIdx.x;
    const int colBase = bx * N;
    const ushort* Bh  = BTh + (size_t)colBase * K;
    const ushort* Bl  = BTl + (size_t)colBase * K;

    constexpr int KC8 = K / 8;
    for (int idx = tid; idx < N * KC8; idx += 512) {
        int n  = idx / KC8;
        int kc = idx % KC8;
        *(int4*)&sBh[n * KP + kc * 8] = *(const int4*)&Bh[(size_t)n * K + kc * 8];
        *(int4*)&sBl[n * KP + kc * 8] = *(const int4*)&Bl[(size_t)n * K + kc * 8];
    }
    __syncthreads();

    const int lane = tid & 63;
    const int wv   = tid >> 6;
    const int lm   = lane & 15, quad = lane >> 4;
    const int rowBase = by * 256 + wv * 32;

    f32x4 acc[2][NJ];
#pragma unroll
    for (int i = 0; i < 2; i++)
#pragma unroll
        for (int j = 0; j < NJ; j++)
#pragma unroll
            for (int t = 0; t < 4; t++) acc[i][j][t] = 0.f;

    for (int ks = 0; ks < KSTEPS; ks++) {
        const int ko = ks * 32 + quad * 8;
        bf16x8 ah[2];
#pragma unroll
        for (int i = 0; i < 2; i++) {
            int r = rowBase + i * 16 + lm;
            ah[i] = loadA8(&Ah[(size_t)r * lda + ko], r < M);
        }
#pragma unroll
        for (int j = 0; j < NJ; j++) {
            int bo = (j * 16 + lm) * KP + ko;
            bf16x8 bh = *(const bf16x8*)&sBh[bo];
            bf16x8 bl = *(const bf16x8*)&sBl[bo];
            acc[0][j] = __builtin_amdgcn_mfma_f32_16x16x32_bf16(ah[0], bh, acc[0][j], 0, 0, 0);
            acc[1][j] = __builtin_amdgcn_mfma_f32_16x16x32_bf16(ah[1], bh, acc[1][j], 0, 0, 0);
            acc[0][j] = __builtin_amdgcn_mfma_f32_16x16x32_bf16(ah[0], bl, acc[0][j], 0, 0, 0);
            acc[1][j] = __builtin_amdgcn_mfma_f32_16x16x32_bf16(ah[1], bl, acc[1][j], 0, 0, 0);
        }
    }

    float bj[NJ];
#pragma unroll
    for (int j = 0; j < NJ; j++) bj[j] = bias ? bias[colBase + j * 16 + lm] : 0.f;

    // C/D layout: col = lane&15, row = quad*4 + reg
#pragma unroll
    for (int i = 0; i < 2; i++) {
#pragma unroll
        for (int t = 0; t < 4; t++) {
            int gr = rowBase + i * 16 + quad * 4 + t;
            if (gr < M) {
#pragma unroll
                for (int j = 0; j < NJ; j++) {
                    int gc = colBase + j * 16 + lm;
                    Cb[(size_t)gr * ldc + gc] = f2bf(acc[i][j][t] + bj[j]);
                }
            }
        }
    }
}

// ---------------------------------------------------------------------------
// In-projection GEMM: A fp32 (h), exact in-register hi/lo split, 3 terms.
// ---------------------------------------------------------------------------
template<int NJ, int KSTEPS>
__global__ __launch_bounds__(512, 4) void gemm_wres_f32(
    const float* __restrict__ A,
    const ushort* __restrict__ BTh, const ushort* __restrict__ BTl,
    const float* __restrict__ bias,
    ushort* __restrict__ Eh, int M, int lda, int ldc)
{
    constexpr int K  = KSTEPS * 32;
    constexpr int N  = NJ * 16;
    constexpr int KP = K + 8;
    extern __shared__ ushort sB[];
    ushort* sBh = sB;
    ushort* sBl = sB + (size_t)N * KP;

    int bx, by;
    if (!swizzle400(blockIdx.x, bx, by)) return;

    const int tid     = threadIdx.x;
    const int colBase = bx * N;
    const ushort* Bh  = BTh + (size_t)colBase * K;
    const ushort* Bl  = BTl + (size_t)colBase * K;

    constexpr int KC8 = K / 8;
    for (int idx = tid; idx < N * KC8; idx += 512) {
        int n  = idx / KC8;
        int kc = idx % KC8;
        *(int4*)&sBh[n * KP + kc * 8] = *(const int4*)&Bh[(size_t)n * K + kc * 8];
        *(int4*)&sBl[n * KP + kc * 8] = *(const int4*)&Bl[(size_t)n * K + kc * 8];
    }
    __syncthreads();

    const int lane = tid & 63;
    const int wv   = tid >> 6;
    const int lm   = lane & 15, quad = lane >> 4;
    const int rowBase = by * 256 + wv * 32;

    f32x4 acc[2][NJ];
#pragma unroll
    for (int i = 0; i < 2; i++)
#pragma unroll
        for (int j = 0; j < NJ; j++)
#pragma unroll
            for (int t = 0; t < 4; t++) acc[i][j][t] = 0.f;

    for (int ks = 0; ks < KSTEPS; ks++) {
        const int ko = ks * 32 + quad * 8;
        bf16x8 ah[2], al[2];
#pragma unroll
        for (int i = 0; i < 2; i++) {
            int r = rowBase + i * 16 + lm;
            float v[8];
            if (r < M) {
                const float* ap = &A[(size_t)r * lda + ko];
                *(float4*)&v[0] = *(const float4*)ap;
                *(float4*)&v[4] = *(const float4*)(ap + 4);
            } else {
#pragma unroll
                for (int q = 0; q < 8; q++) v[q] = 0.f;
            }
#pragma unroll
            for (int q = 0; q < 8; q++) {
                ushort hi = f2bf(v[q]);
                ah[i][q] = (short)hi;
                al[i][q] = (short)f2bf(v[q] - bf2f(hi));
            }
        }
#pragma unroll
        for (int j = 0; j < NJ; j++) {
            int bo = (j * 16 + lm) * KP + ko;
            bf16x8 bh = *(const bf16x8*)&sBh[bo];
            bf16x8 bl = *(const bf16x8*)&sBl[bo];
            acc[0][j] = __builtin_amdgcn_mfma_f32_16x16x32_bf16(ah[0], bh, acc[0][j], 0, 0, 0);
            acc[1][j] = __builtin_amdgcn_mfma_f32_16x16x32_bf16(ah[1], bh, acc[1][j], 0, 0, 0);
            acc[0][j] = __builtin_amdgcn_mfma_f32_16x16x32_bf16(ah[0], bl, acc[0][j], 0, 0, 0);
            acc[1][j] = __builtin_amdgcn_mfma_f32_16x16x32_bf16(ah[1], bl, acc[1][j], 0, 0, 0);
            acc[0][j] = __builtin_amdgcn_mfma_f32_16x16x32_bf16(al[0], bh, acc[0][j], 0, 0, 0);
            acc[1][j] = __builtin_amdgcn_mfma_f32_16x16x32_bf16(al[1], bh, acc[1][j], 0, 0, 0);
        }
    }

    float bj[NJ];
#pragma unroll
    for (int j = 0; j < NJ; j++) bj[j] = bias ? bias[colBase + j * 16 + lm] : 0.f;

#pragma unroll
    for (int i = 0; i < 2; i++) {
#pragma unroll
        for (int t = 0; t < 4; t++) {
            int gr = rowBase + i * 16 + quad * 4 + t;
            if (gr < M) {
#pragma unroll
                for (int j = 0; j < NJ; j++) {
                    int gc = colBase + j * 16 + lm;
                    Eh[(size_t)gr * ldc + gc] = f2bf(acc[i][j][t] + bj[j]);
                }
            }
        }
    }
}

// ---------------------------------------------------------------------------
// merged weight prep + dummy-row init + deg zeroing (replaces memset)
// ---------------------------------------------------------------------------
__global__ void conv_weights(const float* __restrict__ Win, const float* __restrict__ Wm,
                             const float* __restrict__ bm,
                             ushort* __restrict__ winTh, ushort* __restrict__ winTl,
                             ushort* __restrict__ wzyTh, ushort* __restrict__ wzyTl,
                             float* __restrict__ b256, ushort* __restrict__ zy,
                             int* __restrict__ deg) {
    int id = blockIdx.x * 256 + threadIdx.x;
    if (id < 50176) deg[id] = 0;               // histrank runs after this kernel
    if (id < 32768) {
        int k = id >> 7, n = id & 127;
        float v = Win[id];
        ushort hi = f2bf(v);
        winTh[n * 256 + k] = hi;
        winTl[n * 256 + k] = f2bf(v - bf2f(hi));
    } else if (id < 163840) {
        int id2 = id - 32768;                  // 0..131071
        int l = id2 >> 15;
        int r = id2 & 32767;
        int n = r >> 7, k = r & 127;
        float v = (n < 128) ? Wm[l * 33280 + k * 128 + n]
                            : Wm[l * 33280 + (128 + k) * 128 + (n - 128)];
        ushort hi = f2bf(v);
        size_t o = (size_t)l * 32768 + (size_t)n * 128 + k;
        wzyTh[o] = hi;
        wzyTl[o] = f2bf(v - bf2f(hi));
        if (k == 0) b256[l * 256 + n] = (n < 128) ? 0.f : bm[l * 128 + (n - 128)];
    } else if (id < 163968) {
        // dummy node row: z-part = -3.3895e38 (0xFF7F), finite, relu(sum)=0
        zy[(size_t)NN * 256 + (id - 163840)] = 0xFF7F;
    }
}

// ---------------------------------------------------------------------------
// CSR build (padded to multiples of 4) + degree-bin counting sort of nodes.
// Two-level sort: LDS histogram per block (no global atomic contention),
// cross-block per-bin prefix in scan2.
// ---------------------------------------------------------------------------
__global__ void histrank_kernel(const int* __restrict__ dst, int* __restrict__ deg,
                                int* __restrict__ rank) {
    int e = blockIdx.x * 256 + threadIdx.x;
    if (e < NE) rank[e] = atomicAdd(&deg[dst[e]], 1);
}

// scan over PADDED degrees; block-local degree-bin histogram + local rank
__global__ void scan1_kernel(const int* __restrict__ deg, int* __restrict__ csr,
                             int* __restrict__ bsum, int* __restrict__ bhist,
                             int* __restrict__ rankN) {
    __shared__ int s[256];
    __shared__ int hist[256];
    int t = threadIdx.x;
    hist[t] = 0;
    int n = blockIdx.x * 256 + t;
    int d = deg[n];                       // deg array sized 50176, zeroed
    int dp = (d + 3) & ~3;
    int b = dp >> 2; if (b > 255) b = 255;
    __syncthreads();
    if (n < NN) rankN[n] = atomicAdd(&hist[b], 1);   // LDS atomic: block-local rank
    __syncthreads();
    bhist[t * 196 + blockIdx.x] = hist[t];           // bin-major per-block counts
    // padded-degree prefix for csr
    int v = (n < NN) ? dp : 0;
    s[t] = v; __syncthreads();
    for (int dd = 1; dd < 256; dd <<= 1) {
        int u = (t >= dd) ? s[t - dd] : 0;
        __syncthreads();
        s[t] += u;
        __syncthreads();
    }
    csr[n] = s[t] - v;                    // block-local exclusive prefix (all 50176)
    if (t == 255) bsum[blockIdx.x] = s[t];
}

// block-offset scan; per-bin cross-block exclusive prefix (thread t owns bin t);
// DESCENDING cumulative scan of bin totals
__global__ void scan2_kernel(const int* __restrict__ bsum, int* __restrict__ boff,
                             int* __restrict__ bhist, int* __restrict__ ioff) {
    __shared__ int s[256];
    __shared__ int tot[256];
    int t = threadIdx.x;
    int v = (t < 196) ? bsum[t] : 0;
    s[t] = v; __syncthreads();
    for (int d = 1; d < 256; d <<= 1) {
        int u = (t >= d) ? s[t - d] : 0;
        __syncthreads();
        s[t] += u;
        __syncthreads();
    }
    boff[t] = s[t] - v;
    // per-bin cross-block exclusive prefix, in place
    int run = 0;
    for (int blk = 0; blk < 196; blk++) {
        int c = bhist[t * 196 + blk];
        bhist[t * 196 + blk] = run;
        run += c;
    }
    tot[t] = run;                          // total nodes in bin t
    __syncthreads();
    // ioff[b] = sum_{b' > b} tot[b']  (largest-degree bin first)
    int v2 = tot[255 - t];
    s[t] = v2; __syncthreads();
    for (int d = 1; d < 256; d <<= 1) {
        int u = (t >= d) ? s[t - d] : 0;
        __syncthreads();
        s[t] += u;
        __syncthreads();
    }
    ioff[255 - t] = s[t] - v2;
}

// finalize csr; emit perm (degree-sorted descending); fill pad slots
__global__ void scan3_kernel(int* __restrict__ csr, const int* __restrict__ boff,
                             const int* __restrict__ deg, const int* __restrict__ rankN,
                             const int* __restrict__ ioff, const int* __restrict__ bhist,
                             int* __restrict__ perm,
                             int* __restrict__ srcS, float* __restrict__ eaS) {
    int n = blockIdx.x * 256 + threadIdx.x;
    int base = csr[n] + boff[blockIdx.x];
    csr[n] = base;
    if (n < NN) {
        int d = deg[n];
        int dp = (d + 3) & ~3;
        int b = dp >> 2; if (b > 255) b = 255;
        perm[ioff[b] + bhist[b * 196 + blockIdx.x] + rankN[n]] = n;
        float4 z4 = {0.f, 0.f, 0.f, 0.f};
        for (int k = d; k < dp; k++) {
            srcS[base + k] = NN;
            *(float4*)&eaS[(size_t)(base + k) * 4] = z4;
        }
    }
}

// one pass: place each edge's src + edge_attr at its padded-CSR slot
// (plain stores: NT variant measured WORSE — L2 merging beats bypass)
__global__ void scatter_gather_kernel(const int* __restrict__ dst, const int* __restrict__ src,
                                      const int* __restrict__ rank, const int* __restrict__ csr,
                                      const float* __restrict__ ea,
                                      int* __restrict__ srcS, float* __restrict__ eaS) {
    int e = blockIdx.x * 256 + threadIdx.x;
    if (e < NE) {
        int pos = csr[dst[e]] + rank[e];
        srcS[pos] = src[e];
        float4 v = *(const float4*)&ea[(size_t)e * 4];
        *(float4*)&eaS[(size_t)pos * 4] = v;
    }
}

// ---------------------------------------------------------------------------
// Aggregation: 4 nodes/wave (16 lanes/node, 8 ch/lane), uniform 4-batches
// (CSR padded), degree-sorted perm. 3-slot modulo software pipeline:
// batch k+3's z/ea gathers issued when batch k is consumed (~3 substeps of
// flight to cover LLC-hit latency), zero rotation movs (unroll-by-3).
// ---------------------------------------------------------------------------
__global__ __launch_bounds__(256) void agg_kernel(
    const ushort* __restrict__ zy, const float* __restrict__ eaS,
    const float* __restrict__ W3,
    const int* __restrict__ srcS, const int* __restrict__ csr,
    const int* __restrict__ perm,
    ushort* __restrict__ xh,
    const float* __restrict__ Wo, const float* __restrict__ bo,
    float* __restrict__ outp, int lastLayer)
{
    const int wv   = (blockIdx.x * 256 + threadIdx.x) >> 6;  // 0..12499
    const int lane = threadIdx.x & 63;
    const int g    = lane >> 4;          // node group 0..3
    const int li   = lane & 15;
    const int n    = perm[wv * 4 + g];   // degree-sorted node id
    const int c0   = li * 8;             // channel base

    f32x2 w[4][4];
#pragma unroll
    for (int d = 0; d < 4; d++)
#pragma unroll
        for (int q2 = 0; q2 < 4; q2++) {
            float2 t = *(const float2*)&W3[d * HIDD + c0 + 2 * q2];
            w[d][q2] = {t.x, t.y};
        }

    uint4 yu = *(const uint4*)&zy[(size_t)n * 256 + 128 + c0];
    f32x2 y2[4] = {{lo16f(yu.x), hi16f(yu.x)}, {lo16f(yu.y), hi16f(yu.y)},
                   {lo16f(yu.z), hi16f(yu.z)}, {lo16f(yu.w), hi16f(yu.w)}};

    size_t xi = (size_t)n * HIDD + c0;
    uint4 uh = *(const uint4*)&xh[xi];
    f32x2 acc[4] = {{lo16f(uh.x), hi16f(uh.x)},
                    {lo16f(uh.y), hi16f(uh.y)},
                    {lo16f(uh.z), hi16f(uh.z)},
                    {lo16f(uh.w), hi16f(uh.w)}};

    int i     = csr[n];
    int end   = csr[n + 1];
    int nb    = (end - i) >> 2;
    int iLast = end - 4;

#define CL(x)     (((x) <= iLast) ? (x) : iLast)
#define ZLD(sidx) (*(const uint4*)&zy[((size_t)(unsigned)(sidx)) * 256 + c0])
#define ALD(p)    (*(const float4*)&eaS[(size_t)(p) * 4])
#define EDGE(zk, ak) do {                                                   \
        const unsigned int zc_[4] = {(zk).x, (zk).y, (zk).z, (zk).w};       \
        _Pragma("unroll")                                                   \
        for (int q2 = 0; q2 < 4; q2++) {                                    \
            f32x2 m = {lo16f(zc_[q2]), hi16f(zc_[q2])};                     \
            m += y2[q2];                                                    \
            m += (ak).x * w[0][q2];                                         \
            m += (ak).y * w[1][q2];                                         \
            m += (ak).z * w[2][q2];                                         \
            m += (ak).w * w[3][q2];                                         \
            acc[q2].x += fmaxf(m.x, 0.f);                                   \
            acc[q2].y += fmaxf(m.y, 0.f);                                   \
        }                                                                   \
    } while (0)
#define EDGE4(zz0, zz1, zz2, zz3, aa0, aa1, aa2, aa3) \
        do { EDGE(zz0, aa0); EDGE(zz1, aa1); EDGE(zz2, aa2); EDGE(zz3, aa3); } while (0)
#define ISSUE4(zz0, zz1, zz2, zz3, aa0, aa1, aa2, aa3, sv, ip) \
        do { zz0 = ZLD((sv).x); zz1 = ZLD((sv).y); zz2 = ZLD((sv).z); zz3 = ZLD((sv).w); \
             aa0 = ALD(ip); aa1 = ALD((ip) + 1); aa2 = ALD((ip) + 2); aa3 = ALD((ip) + 3); } while (0)

    // 3 pipeline slots (static names -> registers, no scratch)
    uint4  z00, z01, z02, z03, z10, z11, z12, z13, z20, z21, z22, z23;
    float4 a00, a01, a02, a03, a10, a11, a12, a13, a20, a21, a22, a23;
    int4   s0, s1, s2;   // srcS for the batch each slot will issue NEXT

    if (nb > 0) {
        int p1 = CL(i + 4), p2 = CL(i + 8);
        int4 t0 = *(const int4*)&srcS[i];
        int4 t1 = *(const int4*)&srcS[p1];
        int4 t2 = *(const int4*)&srcS[p2];
        ISSUE4(z00, z01, z02, z03, a00, a01, a02, a03, t0, i);
        ISSUE4(z10, z11, z12, z13, a10, a11, a12, a13, t1, p1);
        ISSUE4(z20, z21, z22, z23, a20, a21, a22, a23, t2, p2);
        s0 = *(const int4*)&srcS[CL(i + 12)];
        s1 = *(const int4*)&srcS[CL(i + 16)];
        s2 = *(const int4*)&srcS[CL(i + 20)];
    }
    int k = 0;
    for (; k + 3 <= nb; k += 3) {
        // substep 0: consume batch k (slot0), reissue slot0 <- batch k+3
        EDGE4(z00, z01, z02, z03, a00, a01, a02, a03);
        { int ip = CL(i + 12);
          ISSUE4(z00, z01, z02, z03, a00, a01, a02, a03, s0, ip);
          s0 = *(const int4*)&srcS[CL(i + 24)]; }
        // substep 1: consume batch k+1 (slot1), reissue slot1 <- batch k+4
        EDGE4(z10, z11, z12, z13, a10, a11, a12, a13);
        { int ip = CL(i + 16);
          ISSUE4(z10, z11, z12, z13, a10, a11, a12, a13, s1, ip);
          s1 = *(const int4*)&srcS[CL(i + 28)]; }
        // substep 2: consume batch k+2 (slot2), reissue slot2 <- batch k+5
        EDGE4(z20, z21, z22, z23, a20, a21, a22, a23);
        { int ip = CL(i + 20);
          ISSUE4(z20, z21, z22, z23, a20, a21, a22, a23, s2, ip);
          s2 = *(const int4*)&srcS[CL(i + 32)]; }
        i += 12;
    }
    if (k < nb)     EDGE4(z00, z01, z02, z03, a00, a01, a02, a03);
    if (k + 1 < nb) EDGE4(z10, z11, z12, z13, a10, a11, a12, a13);
#undef CL
#undef ZLD
#undef ALD
#undef EDGE
#undef EDGE4
#undef ISSUE4

    if (!lastLayer) {
        uint4 oh;
        unsigned int* ph = &oh.x;
#pragma unroll
        for (int q2 = 0; q2 < 4; q2++) {
            ushort h0 = f2bf(acc[q2].x), h1 = f2bf(acc[q2].y);
            ph[q2] = (unsigned int)h0 | ((unsigned int)h1 << 16);
        }
        *(uint4*)&xh[xi] = oh;
    } else {
        float p0 = 0.f, p1 = 0.f, p2 = 0.f;
#pragma unroll
        for (int q = 0; q < 8; q++) {
            float xv = (q & 1) ? acc[q >> 1].y : acc[q >> 1].x;
            int ch = c0 + q;
            p0 += xv * Wo[ch * ODIM + 0];
            p1 += xv * Wo[ch * ODIM + 1];
            p2 += xv * Wo[ch * ODIM + 2];
        }
#pragma unroll
        for (int off = 1; off < 16; off <<= 1) {
            p0 += __shfl_xor(p0, off);
            p1 += __shfl_xor(p1, off);
            p2 += __shfl_xor(p2, off);
        }
        if (li == 0) {
            outp[(size_t)n * ODIM + 0] = p0 + bo[0];
            outp[(size_t)n * ODIM + 1] = p1 + bo[1];
            outp[(size_t)n * ODIM + 2] = p2 + bo[2];
        }
    }
}

// ---------------------------------------------------------------------------
extern "C" void kernel_launch(void* const* d_in, const int* in_sizes, int n_in,
                              void* d_out, int out_size, void* d_ws, size_t ws_size,
                              hipStream_t stream)
{
    const float* h     = (const float*)d_in[0];
    const int*   ei    = (const int*)  d_in[1];
    const float* ea    = (const float*)d_in[2];
    const float* W_in  = (const float*)d_in[3];
    const float* b_in  = (const float*)d_in[4];
    const float* W_msg = (const float*)d_in[5];
    const float* b_msg = (const float*)d_in[6];
    const float* W_out = (const float*)d_in[7];
    const float* b_out = (const float*)d_in[8];
    float* out = (float*)d_out;

    // workspace carve-up (~63 MB); EP (padded edges) <= NE + 3*NN = 950000
    ushort* zy     = (ushort*)d_ws;                        // 50001*256 us
    ushort* xh     = zy + 12800256;                        // 6.4M us
    ushort* winTh  = xh + 6400000;                         // 32768
    ushort* winTl  = winTh + 32768;                        // 32768
    ushort* wzyTh  = winTl + 32768;                        // 131072
    ushort* wzyTl  = wzyTh + 131072;                       // 131072
    float*  bias256= (float*)(wzyTl + 131072);             // 1024 f
    float*  eaS    = bias256 + 1024;                       // 3.8M f
    int*    srcS   = (int*)(eaS + 3800000);                // 950k
    int*    rank   = srcS + 950000;                        // 800k
    int*    deg    = rank + 800000;                        // 50176
    int*    csr    = deg + 50176;                          // 50176
    int*    bsum   = csr + 50176;                          // 256
    int*    boff   = bsum + 256;                           // 256
    int*    ioff   = boff + 256;                           // 256
    int*    rankN  = ioff + 256;                           // 50176
    int*    perm   = rankN + 50176;                        // 50176
    int*    bhist  = perm + 50176;                         // 50176 (bin-major)

    const int* srcA = ei;        // edge_index[0]
    const int* dstA = ei + NE;   // edge_index[1]

    // allow >64KB dynamic LDS (in-proj 67.6 KB, zy GEMM 69.6 KB)
    hipFuncSetAttribute((const void*)&gemm_wres_f32<4, 8>,
                        hipFuncAttributeMaxDynamicSharedMemorySize, 2 * 64 * 264 * 2);
    hipFuncSetAttribute((const void*)&gemm_wres<8, 4>,
                        hipFuncAttributeMaxDynamicSharedMemorySize, 2 * 128 * 136 * 2);

    // weight prep (merged) + dummy zy row + deg zeroing (memset folded in)
    conv_weights<<<641, 256, 0, stream>>>(W_in, W_msg, b_msg,
                                          winTh, winTl, wzyTh, wzyTl, bias256, zy, deg);

    // padded CSR build + degree-sort perm (two-level, no global atomic contention)
    histrank_kernel<<<3125, 256, 0, stream>>>(dstA, deg, rank);
    scan1_kernel<<<196, 256, 0, stream>>>(deg, csr, bsum, bhist, rankN);
    scan2_kernel<<<1, 256, 0, stream>>>(bsum, boff, bhist, ioff);
    scan3_kernel<<<196, 256, 0, stream>>>(csr, boff, deg, rankN, ioff, bhist, perm, srcS, eaS);
    scatter_gather_kernel<<<3125, 256, 0, stream>>>(dstA, srcA, rank, csr, ea, srcS, eaS);

    // input projection straight from fp32 h (exact 3-term in-register split)
    gemm_wres_f32<4, 8><<<400, 512, 2 * 64 * 264 * 2, stream>>>(
        h, winTh, winTl, b_in, xh, NN, INDIM, HIDD);

    for (int l = 0; l < NLAYERS; l++) {
        // zy = x @ [W1|W2] + bias, 2-term (A bf16, weight hi/lo), NJ=8
        gemm_wres<8, 4><<<400, 512, 2 * 128 * 136 * 2, stream>>>(
            xh, wzyTh + (size_t)l * 32768, wzyTl + (size_t)l * 32768,
            bias256 + l * 256, zy, NN, HIDD, 256);
        agg_kernel<<<3125, 256, 0, stream>>>(
            zy, eaS, W_msg + (size_t)l * 33280 + 256 * 128,
            srcS, csr, perm, xh, W_out, b_out, out,
            (l == NLAYERS - 1) ? 1 : 0);
    }
}

// Round 8
// 403.117 us; speedup vs baseline: 1.2515x; 1.2515x over previous
//
#include <hip/hip_runtime.h>

#define NN 50000
#define NE 800000
#define INDIM 256
#define HIDD 128
#define ODIM 3
#define EDIM 4
#define NLAYERS 4

typedef __attribute__((ext_vector_type(8))) short bf16x8;
typedef __attribute__((ext_vector_type(4))) float f32x4;
typedef __attribute__((ext_vector_type(2))) float f32x2;

// round-to-nearest-even fp32 -> bf16 bits (finite inputs)
__device__ __forceinline__ ushort f2bf(float f) {
    unsigned int x = __float_as_uint(f);
    unsigned int r = (x + 0x7fffu + ((x >> 16) & 1u)) >> 16;
    return (ushort)r;
}
__device__ __forceinline__ float bf2f(ushort u) {
    return __uint_as_float(((unsigned int)u) << 16);
}
__device__ __forceinline__ float lo16f(unsigned int u) {
    return __uint_as_float(u << 16);
}
__device__ __forceinline__ float hi16f(unsigned int u) {
    return __uint_as_float(u & 0xffff0000u);
}

__device__ __forceinline__ bf16x8 loadA8(const ushort* p, bool ok) {
    if (ok) return *(const bf16x8*)p;
    bf16x8 z = {0, 0, 0, 0, 0, 0, 0, 0};
    return z;
}

// XCD-pairing swizzle: grid 400, col-half pair 8 apart (perf-only hint)
__device__ __forceinline__ bool swizzle400(int b, int& x, int& y) {
    x = (b >> 3) & 1;
    y = (b >> 4) * 8 + (b & 7);
    return y < 196;
}

// ---------------------------------------------------------------------------
// Weights-resident MFMA GEMM, bf16 A (x state), 2-term exact-weight split:
//   C = A@Bh + A@Bl (+bias).  B^T [n][k] hi/lo staged to LDS once;
//   barrier-free k-loop; A frags from global (16B/lane coalesced).
// ---------------------------------------------------------------------------
template<int NJ, int KSTEPS>
__global__ __launch_bounds__(512, 4) void gemm_wres(
    const ushort* __restrict__ Ah,
    const ushort* __restrict__ BTh, const ushort* __restrict__ BTl,
    const float* __restrict__ bias,
    ushort* __restrict__ Cb, int M, int lda, int ldc)
{
    constexpr int K  = KSTEPS * 32;
    constexpr int N  = NJ * 16;
    constexpr int KP = K + 8;                 // padded LDS stride (2-way alias = free)
    extern __shared__ ushort sB[];            // [2][N][KP]
    ushort* sBh = sB;
    ushort* sBl = sB + (size_t)N * KP;

    int bx, by;
    if (!swizzle400(blockIdx.x, bx, by)) return;

    const int tid     = threadIdx.x;
    const int colBase = bx * N;
    const ushort* Bh  = BTh + (size_t)colBase * K;
    const ushort* Bl  = BTl + (size_t)colBase * K;

    constexpr int KC8 = K / 8;
    for (int idx = tid; idx < N * KC8; idx += 512) {
        int n  = idx / KC8;
        int kc = idx % KC8;
        *(int4*)&sBh[n * KP + kc * 8] = *(const int4*)&Bh[(size_t)n * K + kc * 8];
        *(int4*)&sBl[n * KP + kc * 8] = *(const int4*)&Bl[(size_t)n * K + kc * 8];
    }
    __syncthreads();

    const int lane = tid & 63;
    const int wv   = tid >> 6;
    const int lm   = lane & 15, quad = lane >> 4;
    const int rowBase = by * 256 + wv * 32;

    f32x4 acc[2][NJ];
#pragma unroll
    for (int i = 0; i < 2; i++)
#pragma unroll
        for (int j = 0; j < NJ; j++)
#pragma unroll
            for (int t = 0; t < 4; t++) acc[i][j][t] = 0.f;

    for (int ks = 0; ks < KSTEPS; ks++) {
        const int ko = ks * 32 + quad * 8;
        bf16x8 ah[2];
#pragma unroll
        for (int i = 0; i < 2; i++) {
            int r = rowBase + i * 16 + lm;
            ah[i] = loadA8(&Ah[(size_t)r * lda + ko], r < M);
        }
#pragma unroll
        for (int j = 0; j < NJ; j++) {
            int bo = (j * 16 + lm) * KP + ko;
            bf16x8 bh = *(const bf16x8*)&sBh[bo];
            bf16x8 bl = *(const bf16x8*)&sBl[bo];
            acc[0][j] = __builtin_amdgcn_mfma_f32_16x16x32_bf16(ah[0], bh, acc[0][j], 0, 0, 0);
            acc[1][j] = __builtin_amdgcn_mfma_f32_16x16x32_bf16(ah[1], bh, acc[1][j], 0, 0, 0);
            acc[0][j] = __builtin_amdgcn_mfma_f32_16x16x32_bf16(ah[0], bl, acc[0][j], 0, 0, 0);
            acc[1][j] = __builtin_amdgcn_mfma_f32_16x16x32_bf16(ah[1], bl, acc[1][j], 0, 0, 0);
        }
    }

    float bj[NJ];
#pragma unroll
    for (int j = 0; j < NJ; j++) bj[j] = bias ? bias[colBase + j * 16 + lm] : 0.f;

    // C/D layout: col = lane&15, row = quad*4 + reg
#pragma unroll
    for (int i = 0; i < 2; i++) {
#pragma unroll
        for (int t = 0; t < 4; t++) {
            int gr = rowBase + i * 16 + quad * 4 + t;
            if (gr < M) {
#pragma unroll
                for (int j = 0; j < NJ; j++) {
                    int gc = colBase + j * 16 + lm;
                    Cb[(size_t)gr * ldc + gc] = f2bf(acc[i][j][t] + bj[j]);
                }
            }
        }
    }
}

// ---------------------------------------------------------------------------
// In-projection GEMM: A fp32 (h), exact in-register hi/lo split, 3 terms.
// ---------------------------------------------------------------------------
template<int NJ, int KSTEPS>
__global__ __launch_bounds__(512, 4) void gemm_wres_f32(
    const float* __restrict__ A,
    const ushort* __restrict__ BTh, const ushort* __restrict__ BTl,
    const float* __restrict__ bias,
    ushort* __restrict__ Eh, int M, int lda, int ldc)
{
    constexpr int K  = KSTEPS * 32;
    constexpr int N  = NJ * 16;
    constexpr int KP = K + 8;
    extern __shared__ ushort sB[];
    ushort* sBh = sB;
    ushort* sBl = sB + (size_t)N * KP;

    int bx, by;
    if (!swizzle400(blockIdx.x, bx, by)) return;

    const int tid     = threadIdx.x;
    const int colBase = bx * N;
    const ushort* Bh  = BTh + (size_t)colBase * K;
    const ushort* Bl  = BTl + (size_t)colBase * K;

    constexpr int KC8 = K / 8;
    for (int idx = tid; idx < N * KC8; idx += 512) {
        int n  = idx / KC8;
        int kc = idx % KC8;
        *(int4*)&sBh[n * KP + kc * 8] = *(const int4*)&Bh[(size_t)n * K + kc * 8];
        *(int4*)&sBl[n * KP + kc * 8] = *(const int4*)&Bl[(size_t)n * K + kc * 8];
    }
    __syncthreads();

    const int lane = tid & 63;
    const int wv   = tid >> 6;
    const int lm   = lane & 15, quad = lane >> 4;
    const int rowBase = by * 256 + wv * 32;

    f32x4 acc[2][NJ];
#pragma unroll
    for (int i = 0; i < 2; i++)
#pragma unroll
        for (int j = 0; j < NJ; j++)
#pragma unroll
            for (int t = 0; t < 4; t++) acc[i][j][t] = 0.f;

    for (int ks = 0; ks < KSTEPS; ks++) {
        const int ko = ks * 32 + quad * 8;
        bf16x8 ah[2], al[2];
#pragma unroll
        for (int i = 0; i < 2; i++) {
            int r = rowBase + i * 16 + lm;
            float v[8];
            if (r < M) {
                const float* ap = &A[(size_t)r * lda + ko];
                *(float4*)&v[0] = *(const float4*)ap;
                *(float4*)&v[4] = *(const float4*)(ap + 4);
            } else {
#pragma unroll
                for (int q = 0; q < 8; q++) v[q] = 0.f;
            }
#pragma unroll
            for (int q = 0; q < 8; q++) {
                ushort hi = f2bf(v[q]);
                ah[i][q] = (short)hi;
                al[i][q] = (short)f2bf(v[q] - bf2f(hi));
            }
        }
#pragma unroll
        for (int j = 0; j < NJ; j++) {
            int bo = (j * 16 + lm) * KP + ko;
            bf16x8 bh = *(const bf16x8*)&sBh[bo];
            bf16x8 bl = *(const bf16x8*)&sBl[bo];
            acc[0][j] = __builtin_amdgcn_mfma_f32_16x16x32_bf16(ah[0], bh, acc[0][j], 0, 0, 0);
            acc[1][j] = __builtin_amdgcn_mfma_f32_16x16x32_bf16(ah[1], bh, acc[1][j], 0, 0, 0);
            acc[0][j] = __builtin_amdgcn_mfma_f32_16x16x32_bf16(ah[0], bl, acc[0][j], 0, 0, 0);
            acc[1][j] = __builtin_amdgcn_mfma_f32_16x16x32_bf16(ah[1], bl, acc[1][j], 0, 0, 0);
            acc[0][j] = __builtin_amdgcn_mfma_f32_16x16x32_bf16(al[0], bh, acc[0][j], 0, 0, 0);
            acc[1][j] = __builtin_amdgcn_mfma_f32_16x16x32_bf16(al[1], bh, acc[1][j], 0, 0, 0);
        }
    }

    float bj[NJ];
#pragma unroll
    for (int j = 0; j < NJ; j++) bj[j] = bias ? bias[colBase + j * 16 + lm] : 0.f;

#pragma unroll
    for (int i = 0; i < 2; i++) {
#pragma unroll
        for (int t = 0; t < 4; t++) {
            int gr = rowBase + i * 16 + quad * 4 + t;
            if (gr < M) {
#pragma unroll
                for (int j = 0; j < NJ; j++) {
                    int gc = colBase + j * 16 + lm;
                    Eh[(size_t)gr * ldc + gc] = f2bf(acc[i][j][t] + bj[j]);
                }
            }
        }
    }
}

// ---------------------------------------------------------------------------
// merged weight prep + dummy-row init + deg zeroing (replaces memset)
// ---------------------------------------------------------------------------
__global__ void conv_weights(const float* __restrict__ Win, const float* __restrict__ Wm,
                             const float* __restrict__ bm,
                             ushort* __restrict__ winTh, ushort* __restrict__ winTl,
                             ushort* __restrict__ wzyTh, ushort* __restrict__ wzyTl,
                             float* __restrict__ b256, ushort* __restrict__ zy,
                             int* __restrict__ deg) {
    int id = blockIdx.x * 256 + threadIdx.x;
    if (id < 50176) deg[id] = 0;               // histrank runs after this kernel
    if (id < 32768) {
        int k = id >> 7, n = id & 127;
        float v = Win[id];
        ushort hi = f2bf(v);
        winTh[n * 256 + k] = hi;
        winTl[n * 256 + k] = f2bf(v - bf2f(hi));
    } else if (id < 163840) {
        int id2 = id - 32768;                  // 0..131071
        int l = id2 >> 15;
        int r = id2 & 32767;
        int n = r >> 7, k = r & 127;
        float v = (n < 128) ? Wm[l * 33280 + k * 128 + n]
                            : Wm[l * 33280 + (128 + k) * 128 + (n - 128)];
        ushort hi = f2bf(v);
        size_t o = (size_t)l * 32768 + (size_t)n * 128 + k;
        wzyTh[o] = hi;
        wzyTl[o] = f2bf(v - bf2f(hi));
        if (k == 0) b256[l * 256 + n] = (n < 128) ? 0.f : bm[l * 128 + (n - 128)];
    } else if (id < 163968) {
        // dummy node row: z-part = -3.3895e38 (0xFF7F), finite, relu(sum)=0
        zy[(size_t)NN * 256 + (id - 163840)] = 0xFF7F;
    }
}

// ---------------------------------------------------------------------------
// CSR build (padded to multiples of 4) + degree-bin counting sort of nodes.
// Two-level sort: LDS histogram per block (no global atomic contention),
// cross-block per-bin prefix in scan2.
// ---------------------------------------------------------------------------
__global__ void histrank_kernel(const int* __restrict__ dst, int* __restrict__ deg,
                                int* __restrict__ rank) {
    int e = blockIdx.x * 256 + threadIdx.x;
    if (e < NE) rank[e] = atomicAdd(&deg[dst[e]], 1);
}

// scan over PADDED degrees; block-local degree-bin histogram + local rank
__global__ void scan1_kernel(const int* __restrict__ deg, int* __restrict__ csr,
                             int* __restrict__ bsum, int* __restrict__ bhist,
                             int* __restrict__ rankN) {
    __shared__ int s[256];
    __shared__ int hist[256];
    int t = threadIdx.x;
    hist[t] = 0;
    int n = blockIdx.x * 256 + t;
    int d = deg[n];                       // deg array sized 50176, zeroed
    int dp = (d + 3) & ~3;
    int b = dp >> 2; if (b > 255) b = 255;
    __syncthreads();
    if (n < NN) rankN[n] = atomicAdd(&hist[b], 1);   // LDS atomic: block-local rank
    __syncthreads();
    bhist[t * 196 + blockIdx.x] = hist[t];           // bin-major per-block counts
    // padded-degree prefix for csr
    int v = (n < NN) ? dp : 0;
    s[t] = v; __syncthreads();
    for (int dd = 1; dd < 256; dd <<= 1) {
        int u = (t >= dd) ? s[t - dd] : 0;
        __syncthreads();
        s[t] += u;
        __syncthreads();
    }
    csr[n] = s[t] - v;                    // block-local exclusive prefix (all 50176)
    if (t == 255) bsum[blockIdx.x] = s[t];
}

// block-offset scan; per-bin cross-block exclusive prefix (thread t owns bin t);
// DESCENDING cumulative scan of bin totals
__global__ void scan2_kernel(const int* __restrict__ bsum, int* __restrict__ boff,
                             int* __restrict__ bhist, int* __restrict__ ioff) {
    __shared__ int s[256];
    __shared__ int tot[256];
    int t = threadIdx.x;
    int v = (t < 196) ? bsum[t] : 0;
    s[t] = v; __syncthreads();
    for (int d = 1; d < 256; d <<= 1) {
        int u = (t >= d) ? s[t - d] : 0;
        __syncthreads();
        s[t] += u;
        __syncthreads();
    }
    boff[t] = s[t] - v;
    // per-bin cross-block exclusive prefix, in place
    int run = 0;
    for (int blk = 0; blk < 196; blk++) {
        int c = bhist[t * 196 + blk];
        bhist[t * 196 + blk] = run;
        run += c;
    }
    tot[t] = run;                          // total nodes in bin t
    __syncthreads();
    // ioff[b] = sum_{b' > b} tot[b']  (largest-degree bin first)
    int v2 = tot[255 - t];
    s[t] = v2; __syncthreads();
    for (int d = 1; d < 256; d <<= 1) {
        int u = (t >= d) ? s[t - d] : 0;
        __syncthreads();
        s[t] += u;
        __syncthreads();
    }
    ioff[255 - t] = s[t] - v2;
}

// finalize csr; emit perm (degree-sorted descending); fill pad slots
__global__ void scan3_kernel(int* __restrict__ csr, const int* __restrict__ boff,
                             const int* __restrict__ deg, const int* __restrict__ rankN,
                             const int* __restrict__ ioff, const int* __restrict__ bhist,
                             int* __restrict__ perm,
                             int* __restrict__ srcS, float* __restrict__ eaS) {
    int n = blockIdx.x * 256 + threadIdx.x;
    int base = csr[n] + boff[blockIdx.x];
    csr[n] = base;
    if (n < NN) {
        int d = deg[n];
        int dp = (d + 3) & ~3;
        int b = dp >> 2; if (b > 255) b = 255;
        perm[ioff[b] + bhist[b * 196 + blockIdx.x] + rankN[n]] = n;
        float4 z4 = {0.f, 0.f, 0.f, 0.f};
        for (int k = d; k < dp; k++) {
            srcS[base + k] = NN;
            *(float4*)&eaS[(size_t)(base + k) * 4] = z4;
        }
    }
}

// one pass: place each edge's src + edge_attr at its padded-CSR slot
// (plain stores: NT variant measured WORSE — L2 merging beats bypass)
__global__ void scatter_gather_kernel(const int* __restrict__ dst, const int* __restrict__ src,
                                      const int* __restrict__ rank, const int* __restrict__ csr,
                                      const float* __restrict__ ea,
                                      int* __restrict__ srcS, float* __restrict__ eaS) {
    int e = blockIdx.x * 256 + threadIdx.x;
    if (e < NE) {
        int pos = csr[dst[e]] + rank[e];
        srcS[pos] = src[e];
        float4 v = *(const float4*)&ea[(size_t)e * 4];
        *(float4*)&eaS[(size_t)pos * 4] = v;
    }
}

// ---------------------------------------------------------------------------
// Aggregation (best-known round-2 structure): 4 nodes/wave (16 lanes/node,
// 8 ch/lane), uniform 4-batches (CSR padded), degree-sorted perm, 2-stage
// software pipeline: idx 2 batches ahead, z/ea gathers 1 batch ahead.
// 60 VGPR -> ~30% occupancy; deeper pipelining (3-slot, 136 VGPR) measured
// WORSE (64.7µs, occ 9%); channel-split (2x waves) measured neutral-worse.
// At ~100MB FETCH / ~39µs = 2.6 TB/s random-gather HBM roofline.
// ---------------------------------------------------------------------------
__global__ __launch_bounds__(256) void agg_kernel(
    const ushort* __restrict__ zy, const float* __restrict__ eaS,
    const float* __restrict__ W3,
    const int* __restrict__ srcS, const int* __restrict__ csr,
    const int* __restrict__ perm,
    ushort* __restrict__ xh,
    const float* __restrict__ Wo, const float* __restrict__ bo,
    float* __restrict__ outp, int lastLayer)
{
    const int wv   = (blockIdx.x * 256 + threadIdx.x) >> 6;  // 0..12499
    const int lane = threadIdx.x & 63;
    const int g    = lane >> 4;          // node group 0..3
    const int li   = lane & 15;
    const int n    = perm[wv * 4 + g];   // degree-sorted node id
    const int c0   = li * 8;             // channel base

    f32x2 w[4][4];
#pragma unroll
    for (int d = 0; d < 4; d++)
#pragma unroll
        for (int q2 = 0; q2 < 4; q2++) {
            float2 t = *(const float2*)&W3[d * HIDD + c0 + 2 * q2];
            w[d][q2] = {t.x, t.y};
        }

    uint4 yu = *(const uint4*)&zy[(size_t)n * 256 + 128 + c0];
    f32x2 y2[4] = {{lo16f(yu.x), hi16f(yu.x)}, {lo16f(yu.y), hi16f(yu.y)},
                   {lo16f(yu.z), hi16f(yu.z)}, {lo16f(yu.w), hi16f(yu.w)}};

    size_t xi = (size_t)n * HIDD + c0;
    uint4 uh = *(const uint4*)&xh[xi];
    f32x2 acc[4] = {{lo16f(uh.x), hi16f(uh.x)},
                    {lo16f(uh.y), hi16f(uh.y)},
                    {lo16f(uh.z), hi16f(uh.z)},
                    {lo16f(uh.w), hi16f(uh.w)}};

    int i   = csr[n];
    int end = csr[n + 1];
    int nb  = (end - i) >> 2;
    int iLast = end - 4;

#define ZLD(sidx) (*(const uint4*)&zy[((size_t)(unsigned)(sidx)) * 256 + c0])
#define ALD(p)    (*(const float4*)&eaS[(size_t)(p) * 4])
#define EDGE(zk, ak) do {                                                   \
        const unsigned int zc_[4] = {(zk).x, (zk).y, (zk).z, (zk).w};       \
        _Pragma("unroll")                                                   \
        for (int q2 = 0; q2 < 4; q2++) {                                    \
            f32x2 m = {lo16f(zc_[q2]), hi16f(zc_[q2])};                     \
            m += y2[q2];                                                    \
            m += (ak).x * w[0][q2];                                         \
            m += (ak).y * w[1][q2];                                         \
            m += (ak).z * w[2][q2];                                         \
            m += (ak).w * w[3][q2];                                         \
            acc[q2].x += fmaxf(m.x, 0.f);                                   \
            acc[q2].y += fmaxf(m.y, 0.f);                                   \
        }                                                                   \
    } while (0)

    uint4 z0, z1, z2, z3;
    float4 a0, a1, a2, a3;
    int4 sn;
    if (nb > 0) {
        int4 sc = *(const int4*)&srcS[i];
        int i1 = (i + 4 <= iLast) ? i + 4 : iLast;
        sn = *(const int4*)&srcS[i1];
        z0 = ZLD(sc.x); z1 = ZLD(sc.y); z2 = ZLD(sc.z); z3 = ZLD(sc.w);
        a0 = ALD(i); a1 = ALD(i + 1); a2 = ALD(i + 2); a3 = ALD(i + 3);
    }
    for (int k = 0; k < nb; k++) {
        int inext = (i + 4 <= iLast) ? i + 4 : iLast;   // batch k+1 (clamped)
        int inn   = (i + 8 <= iLast) ? i + 8 : iLast;   // batch k+2 (clamped)
        // issue next batch's gathers BEFORE consuming current batch
        uint4 n0 = ZLD(sn.x), n1 = ZLD(sn.y), n2 = ZLD(sn.z), n3 = ZLD(sn.w);
        float4 b0 = ALD(inext), b1 = ALD(inext + 1), b2 = ALD(inext + 2), b3 = ALD(inext + 3);
        int4 snn = *(const int4*)&srcS[inn];
        // consume current batch (loads already in flight since last iter)
        EDGE(z0, a0); EDGE(z1, a1); EDGE(z2, a2); EDGE(z3, a3);
        z0 = n0; z1 = n1; z2 = n2; z3 = n3;
        a0 = b0; a1 = b1; a2 = b2; a3 = b3;
        sn = snn;
        i += 4;
    }
#undef ZLD
#undef ALD
#undef EDGE

    if (!lastLayer) {
        uint4 oh;
        unsigned int* ph = &oh.x;
#pragma unroll
        for (int q2 = 0; q2 < 4; q2++) {
            ushort h0 = f2bf(acc[q2].x), h1 = f2bf(acc[q2].y);
            ph[q2] = (unsigned int)h0 | ((unsigned int)h1 << 16);
        }
        *(uint4*)&xh[xi] = oh;
    } else {
        float p0 = 0.f, p1 = 0.f, p2 = 0.f;
#pragma unroll
        for (int q = 0; q < 8; q++) {
            float xv = (q & 1) ? acc[q >> 1].y : acc[q >> 1].x;
            int ch = c0 + q;
            p0 += xv * Wo[ch * ODIM + 0];
            p1 += xv * Wo[ch * ODIM + 1];
            p2 += xv * Wo[ch * ODIM + 2];
        }
#pragma unroll
        for (int off = 1; off < 16; off <<= 1) {
            p0 += __shfl_xor(p0, off);
            p1 += __shfl_xor(p1, off);
            p2 += __shfl_xor(p2, off);
        }
        if (li == 0) {
            outp[(size_t)n * ODIM + 0] = p0 + bo[0];
            outp[(size_t)n * ODIM + 1] = p1 + bo[1];
            outp[(size_t)n * ODIM + 2] = p2 + bo[2];
        }
    }
}

// ---------------------------------------------------------------------------
extern "C" void kernel_launch(void* const* d_in, const int* in_sizes, int n_in,
                              void* d_out, int out_size, void* d_ws, size_t ws_size,
                              hipStream_t stream)
{
    const float* h     = (const float*)d_in[0];
    const int*   ei    = (const int*)  d_in[1];
    const float* ea    = (const float*)d_in[2];
    const float* W_in  = (const float*)d_in[3];
    const float* b_in  = (const float*)d_in[4];
    const float* W_msg = (const float*)d_in[5];
    const float* b_msg = (const float*)d_in[6];
    const float* W_out = (const float*)d_in[7];
    const float* b_out = (const float*)d_in[8];
    float* out = (float*)d_out;

    // workspace carve-up (~63 MB); EP (padded edges) <= NE + 3*NN = 950000
    ushort* zy     = (ushort*)d_ws;                        // 50001*256 us
    ushort* xh     = zy + 12800256;                        // 6.4M us
    ushort* winTh  = xh + 6400000;                         // 32768
    ushort* winTl  = winTh + 32768;                        // 32768
    ushort* wzyTh  = winTl + 32768;                        // 131072
    ushort* wzyTl  = wzyTh + 131072;                       // 131072
    float*  bias256= (float*)(wzyTl + 131072);             // 1024 f
    float*  eaS    = bias256 + 1024;                       // 3.8M f
    int*    srcS   = (int*)(eaS + 3800000);                // 950k
    int*    rank   = srcS + 950000;                        // 800k
    int*    deg    = rank + 800000;                        // 50176
    int*    csr    = deg + 50176;                          // 50176
    int*    bsum   = csr + 50176;                          // 256
    int*    boff   = bsum + 256;                           // 256
    int*    ioff   = boff + 256;                           // 256
    int*    rankN  = ioff + 256;                           // 50176
    int*    perm   = rankN + 50176;                        // 50176
    int*    bhist  = perm + 50176;                         // 50176 (bin-major)

    const int* srcA = ei;        // edge_index[0]
    const int* dstA = ei + NE;   // edge_index[1]

    // allow >64KB dynamic LDS (in-proj 67.6 KB, zy GEMM 69.6 KB)
    hipFuncSetAttribute((const void*)&gemm_wres_f32<4, 8>,
                        hipFuncAttributeMaxDynamicSharedMemorySize, 2 * 64 * 264 * 2);
    hipFuncSetAttribute((const void*)&gemm_wres<8, 4>,
                        hipFuncAttributeMaxDynamicSharedMemorySize, 2 * 128 * 136 * 2);

    // weight prep (merged) + dummy zy row + deg zeroing (memset folded in)
    conv_weights<<<641, 256, 0, stream>>>(W_in, W_msg, b_msg,
                                          winTh, winTl, wzyTh, wzyTl, bias256, zy, deg);

    // padded CSR build + degree-sort perm (two-level, no global atomic contention)
    histrank_kernel<<<3125, 256, 0, stream>>>(dstA, deg, rank);
    scan1_kernel<<<196, 256, 0, stream>>>(deg, csr, bsum, bhist, rankN);
    scan2_kernel<<<1, 256, 0, stream>>>(bsum, boff, bhist, ioff);
    scan3_kernel<<<196, 256, 0, stream>>>(csr, boff, deg, rankN, ioff, bhist, perm, srcS, eaS);
    scatter_gather_kernel<<<3125, 256, 0, stream>>>(dstA, srcA, rank, csr, ea, srcS, eaS);

    // input projection straight from fp32 h (exact 3-term in-register split)
    gemm_wres_f32<4, 8><<<400, 512, 2 * 64 * 264 * 2, stream>>>(
        h, winTh, winTl, b_in, xh, NN, INDIM, HIDD);

    for (int l = 0; l < NLAYERS; l++) {
        // zy = x @ [W1|W2] + bias, 2-term (A bf16, weight hi/lo), NJ=8
        gemm_wres<8, 4><<<400, 512, 2 * 128 * 136 * 2, stream>>>(
            xh, wzyTh + (size_t)l * 32768, wzyTl + (size_t)l * 32768,
            bias256 + l * 256, zy, NN, HIDD, 256);
        agg_kernel<<<3125, 256, 0, stream>>>(
            zy, eaS, W_msg + (size_t)l * 33280 + 256 * 128,
            srcS, csr, perm, xh, W_out, b_out, out,
            (l == NLAYERS - 1) ? 1 : 0);
    }
}

// Round 9
// 402.564 us; speedup vs baseline: 1.2532x; 1.0014x over previous
//
#include <hip/hip_runtime.h>

#define NN 50000
#define NE 800000
#define INDIM 256
#define HIDD 128
#define ODIM 3
#define EDIM 4
#define NLAYERS 4

typedef __attribute__((ext_vector_type(8))) short bf16x8;
typedef __attribute__((ext_vector_type(4))) float f32x4;
typedef __attribute__((ext_vector_type(2))) float f32x2;

// round-to-nearest-even fp32 -> bf16 bits (finite inputs)
__device__ __forceinline__ ushort f2bf(float f) {
    unsigned int x = __float_as_uint(f);
    unsigned int r = (x + 0x7fffu + ((x >> 16) & 1u)) >> 16;
    return (ushort)r;
}
__device__ __forceinline__ float bf2f(ushort u) {
    return __uint_as_float(((unsigned int)u) << 16);
}
__device__ __forceinline__ float lo16f(unsigned int u) {
    return __uint_as_float(u << 16);
}
__device__ __forceinline__ float hi16f(unsigned int u) {
    return __uint_as_float(u & 0xffff0000u);
}

__device__ __forceinline__ bf16x8 loadA8(const ushort* p, bool ok) {
    if (ok) return *(const bf16x8*)p;
    bf16x8 z = {0, 0, 0, 0, 0, 0, 0, 0};
    return z;
}

// XCD-pairing swizzle: grid 400, col-half pair 8 apart (perf-only hint)
__device__ __forceinline__ bool swizzle400(int b, int& x, int& y) {
    x = (b >> 3) & 1;
    y = (b >> 4) * 8 + (b & 7);
    return y < 196;
}

// ---------------------------------------------------------------------------
// Weights-resident MFMA GEMM, bf16 A (x state), 2-term exact-weight split:
//   C = A@Bh + A@Bl (+bias).  B^T [n][k] hi/lo staged to LDS once;
//   barrier-free k-loop; A frags from global (16B/lane coalesced).
// ---------------------------------------------------------------------------
template<int NJ, int KSTEPS>
__global__ __launch_bounds__(512, 4) void gemm_wres(
    const ushort* __restrict__ Ah,
    const ushort* __restrict__ BTh, const ushort* __restrict__ BTl,
    const float* __restrict__ bias,
    ushort* __restrict__ Cb, int M, int lda, int ldc)
{
    constexpr int K  = KSTEPS * 32;
    constexpr int N  = NJ * 16;
    constexpr int KP = K + 8;                 // padded LDS stride (2-way alias = free)
    extern __shared__ ushort sB[];            // [2][N][KP]
    ushort* sBh = sB;
    ushort* sBl = sB + (size_t)N * KP;

    int bx, by;
    if (!swizzle400(blockIdx.x, bx, by)) return;

    const int tid     = threadIdx.x;
    const int colBase = bx * N;
    const ushort* Bh  = BTh + (size_t)colBase * K;
    const ushort* Bl  = BTl + (size_t)colBase * K;

    constexpr int KC8 = K / 8;
    for (int idx = tid; idx < N * KC8; idx += 512) {
        int n  = idx / KC8;
        int kc = idx % KC8;
        *(int4*)&sBh[n * KP + kc * 8] = *(const int4*)&Bh[(size_t)n * K + kc * 8];
        *(int4*)&sBl[n * KP + kc * 8] = *(const int4*)&Bl[(size_t)n * K + kc * 8];
    }
    __syncthreads();

    const int lane = tid & 63;
    const int wv   = tid >> 6;
    const int lm   = lane & 15, quad = lane >> 4;
    const int rowBase = by * 256 + wv * 32;

    f32x4 acc[2][NJ];
#pragma unroll
    for (int i = 0; i < 2; i++)
#pragma unroll
        for (int j = 0; j < NJ; j++)
#pragma unroll
            for (int t = 0; t < 4; t++) acc[i][j][t] = 0.f;

    for (int ks = 0; ks < KSTEPS; ks++) {
        const int ko = ks * 32 + quad * 8;
        bf16x8 ah[2];
#pragma unroll
        for (int i = 0; i < 2; i++) {
            int r = rowBase + i * 16 + lm;
            ah[i] = loadA8(&Ah[(size_t)r * lda + ko], r < M);
        }
#pragma unroll
        for (int j = 0; j < NJ; j++) {
            int bo = (j * 16 + lm) * KP + ko;
            bf16x8 bh = *(const bf16x8*)&sBh[bo];
            bf16x8 bl = *(const bf16x8*)&sBl[bo];
            acc[0][j] = __builtin_amdgcn_mfma_f32_16x16x32_bf16(ah[0], bh, acc[0][j], 0, 0, 0);
            acc[1][j] = __builtin_amdgcn_mfma_f32_16x16x32_bf16(ah[1], bh, acc[1][j], 0, 0, 0);
            acc[0][j] = __builtin_amdgcn_mfma_f32_16x16x32_bf16(ah[0], bl, acc[0][j], 0, 0, 0);
            acc[1][j] = __builtin_amdgcn_mfma_f32_16x16x32_bf16(ah[1], bl, acc[1][j], 0, 0, 0);
        }
    }

    float bj[NJ];
#pragma unroll
    for (int j = 0; j < NJ; j++) bj[j] = bias ? bias[colBase + j * 16 + lm] : 0.f;

    // C/D layout: col = lane&15, row = quad*4 + reg
#pragma unroll
    for (int i = 0; i < 2; i++) {
#pragma unroll
        for (int t = 0; t < 4; t++) {
            int gr = rowBase + i * 16 + quad * 4 + t;
            if (gr < M) {
#pragma unroll
                for (int j = 0; j < NJ; j++) {
                    int gc = colBase + j * 16 + lm;
                    Cb[(size_t)gr * ldc + gc] = f2bf(acc[i][j][t] + bj[j]);
                }
            }
        }
    }
}

// ---------------------------------------------------------------------------
// In-projection GEMM: A fp32 (h), exact in-register hi/lo split, 3 terms.
// ---------------------------------------------------------------------------
template<int NJ, int KSTEPS>
__global__ __launch_bounds__(512, 4) void gemm_wres_f32(
    const float* __restrict__ A,
    const ushort* __restrict__ BTh, const ushort* __restrict__ BTl,
    const float* __restrict__ bias,
    ushort* __restrict__ Eh, int M, int lda, int ldc)
{
    constexpr int K  = KSTEPS * 32;
    constexpr int N  = NJ * 16;
    constexpr int KP = K + 8;
    extern __shared__ ushort sB[];
    ushort* sBh = sB;
    ushort* sBl = sB + (size_t)N * KP;

    int bx, by;
    if (!swizzle400(blockIdx.x, bx, by)) return;

    const int tid     = threadIdx.x;
    const int colBase = bx * N;
    const ushort* Bh  = BTh + (size_t)colBase * K;
    const ushort* Bl  = BTl + (size_t)colBase * K;

    constexpr int KC8 = K / 8;
    for (int idx = tid; idx < N * KC8; idx += 512) {
        int n  = idx / KC8;
        int kc = idx % KC8;
        *(int4*)&sBh[n * KP + kc * 8] = *(const int4*)&Bh[(size_t)n * K + kc * 8];
        *(int4*)&sBl[n * KP + kc * 8] = *(const int4*)&Bl[(size_t)n * K + kc * 8];
    }
    __syncthreads();

    const int lane = tid & 63;
    const int wv   = tid >> 6;
    const int lm   = lane & 15, quad = lane >> 4;
    const int rowBase = by * 256 + wv * 32;

    f32x4 acc[2][NJ];
#pragma unroll
    for (int i = 0; i < 2; i++)
#pragma unroll
        for (int j = 0; j < NJ; j++)
#pragma unroll
            for (int t = 0; t < 4; t++) acc[i][j][t] = 0.f;

    for (int ks = 0; ks < KSTEPS; ks++) {
        const int ko = ks * 32 + quad * 8;
        bf16x8 ah[2], al[2];
#pragma unroll
        for (int i = 0; i < 2; i++) {
            int r = rowBase + i * 16 + lm;
            float v[8];
            if (r < M) {
                const float* ap = &A[(size_t)r * lda + ko];
                *(float4*)&v[0] = *(const float4*)ap;
                *(float4*)&v[4] = *(const float4*)(ap + 4);
            } else {
#pragma unroll
                for (int q = 0; q < 8; q++) v[q] = 0.f;
            }
#pragma unroll
            for (int q = 0; q < 8; q++) {
                ushort hi = f2bf(v[q]);
                ah[i][q] = (short)hi;
                al[i][q] = (short)f2bf(v[q] - bf2f(hi));
            }
        }
#pragma unroll
        for (int j = 0; j < NJ; j++) {
            int bo = (j * 16 + lm) * KP + ko;
            bf16x8 bh = *(const bf16x8*)&sBh[bo];
            bf16x8 bl = *(const bf16x8*)&sBl[bo];
            acc[0][j] = __builtin_amdgcn_mfma_f32_16x16x32_bf16(ah[0], bh, acc[0][j], 0, 0, 0);
            acc[1][j] = __builtin_amdgcn_mfma_f32_16x16x32_bf16(ah[1], bh, acc[1][j], 0, 0, 0);
            acc[0][j] = __builtin_amdgcn_mfma_f32_16x16x32_bf16(ah[0], bl, acc[0][j], 0, 0, 0);
            acc[1][j] = __builtin_amdgcn_mfma_f32_16x16x32_bf16(ah[1], bl, acc[1][j], 0, 0, 0);
            acc[0][j] = __builtin_amdgcn_mfma_f32_16x16x32_bf16(al[0], bh, acc[0][j], 0, 0, 0);
            acc[1][j] = __builtin_amdgcn_mfma_f32_16x16x32_bf16(al[1], bh, acc[1][j], 0, 0, 0);
        }
    }

    float bj[NJ];
#pragma unroll
    for (int j = 0; j < NJ; j++) bj[j] = bias ? bias[colBase + j * 16 + lm] : 0.f;

#pragma unroll
    for (int i = 0; i < 2; i++) {
#pragma unroll
        for (int t = 0; t < 4; t++) {
            int gr = rowBase + i * 16 + quad * 4 + t;
            if (gr < M) {
#pragma unroll
                for (int j = 0; j < NJ; j++) {
                    int gc = colBase + j * 16 + lm;
                    Eh[(size_t)gr * ldc + gc] = f2bf(acc[i][j][t] + bj[j]);
                }
            }
        }
    }
}

// ---------------------------------------------------------------------------
// merged weight prep + dummy-row init + deg8 zeroing (replaces memset)
// ---------------------------------------------------------------------------
__global__ void conv_weights(const float* __restrict__ Win, const float* __restrict__ Wm,
                             const float* __restrict__ bm,
                             ushort* __restrict__ winTh, ushort* __restrict__ winTl,
                             ushort* __restrict__ wzyTh, ushort* __restrict__ wzyTl,
                             float* __restrict__ b256, ushort* __restrict__ zy,
                             int* __restrict__ deg8) {
    int id = blockIdx.x * 256 + threadIdx.x;
    if (id < 401408) deg8[id] = 0;             // 8 x 50176 replicated histogram
    if (id < 32768) {
        int k = id >> 7, n = id & 127;
        float v = Win[id];
        ushort hi = f2bf(v);
        winTh[n * 256 + k] = hi;
        winTl[n * 256 + k] = f2bf(v - bf2f(hi));
    } else if (id < 163840) {
        int id2 = id - 32768;                  // 0..131071
        int l = id2 >> 15;
        int r = id2 & 32767;
        int n = r >> 7, k = r & 127;
        float v = (n < 128) ? Wm[l * 33280 + k * 128 + n]
                            : Wm[l * 33280 + (128 + k) * 128 + (n - 128)];
        ushort hi = f2bf(v);
        size_t o = (size_t)l * 32768 + (size_t)n * 128 + k;
        wzyTh[o] = hi;
        wzyTl[o] = f2bf(v - bf2f(hi));
        if (k == 0) b256[l * 256 + n] = (n < 128) ? 0.f : bm[l * 128 + (n - 128)];
    } else if (id < 163968) {
        // dummy node row: z-part = -3.3895e38 (0xFF7F), finite, relu(sum)=0
        zy[(size_t)NN * 256 + (id - 163840)] = 0xFF7F;
    }
}

// ---------------------------------------------------------------------------
// CSR build (padded to multiples of 4) + degree-bin counting sort of nodes.
// 8-way replicated degree histogram (replica = blockIdx&7 ~ XCD under
// round-robin dispatch): splits the 16-deep per-address atomic collision
// into 8 x 2-deep, keeps replica lines XCD-local. rank packs (local<<3)|rep.
// ---------------------------------------------------------------------------
__global__ void histrank_kernel(const int* __restrict__ dst, int* __restrict__ deg8,
                                int* __restrict__ rank) {
    int e = blockIdx.x * 256 + threadIdx.x;
    if (e < NE) {
        int rep = blockIdx.x & 7;
        int r = atomicAdd(&deg8[rep * 50176 + dst[e]], 1);
        rank[e] = (r << 3) | rep;
    }
}

// fold deg8 counts -> per-(node,replica) exclusive offsets (in place), total
// degree -> deg[]; padded-degree prefix for csr; block-local degree-bin
// histogram + local rank (LDS atomics, no global contention)
__global__ void scan1_kernel(int* __restrict__ deg8, int* __restrict__ deg,
                             int* __restrict__ csr,
                             int* __restrict__ bsum, int* __restrict__ bhist,
                             int* __restrict__ rankN) {
    __shared__ int s[256];
    __shared__ int hist[256];
    int t = threadIdx.x;
    hist[t] = 0;
    int n = blockIdx.x * 256 + t;
    int off = 0;
#pragma unroll
    for (int r = 0; r < 8; r++) {
        int c = deg8[r * 50176 + n];
        deg8[r * 50176 + n] = off;
        off += c;
    }
    int d = off;                          // total degree
    deg[n] = d;
    int dp = (d + 3) & ~3;
    int b = dp >> 2; if (b > 255) b = 255;
    __syncthreads();
    if (n < NN) rankN[n] = atomicAdd(&hist[b], 1);   // LDS atomic: block-local rank
    __syncthreads();
    bhist[t * 196 + blockIdx.x] = hist[t];           // bin-major per-block counts
    int v = (n < NN) ? dp : 0;
    s[t] = v; __syncthreads();
    for (int dd = 1; dd < 256; dd <<= 1) {
        int u = (t >= dd) ? s[t - dd] : 0;
        __syncthreads();
        s[t] += u;
        __syncthreads();
    }
    csr[n] = s[t] - v;                    // block-local exclusive prefix (all 50176)
    if (t == 255) bsum[blockIdx.x] = s[t];
}

// block-offset scan; per-bin cross-block exclusive prefix (thread t owns bin t);
// DESCENDING cumulative scan of bin totals
__global__ void scan2_kernel(const int* __restrict__ bsum, int* __restrict__ boff,
                             int* __restrict__ bhist, int* __restrict__ ioff) {
    __shared__ int s[256];
    __shared__ int tot[256];
    int t = threadIdx.x;
    int v = (t < 196) ? bsum[t] : 0;
    s[t] = v; __syncthreads();
    for (int d = 1; d < 256; d <<= 1) {
        int u = (t >= d) ? s[t - d] : 0;
        __syncthreads();
        s[t] += u;
        __syncthreads();
    }
    boff[t] = s[t] - v;
    // per-bin cross-block exclusive prefix, in place
    int run = 0;
    for (int blk = 0; blk < 196; blk++) {
        int c = bhist[t * 196 + blk];
        bhist[t * 196 + blk] = run;
        run += c;
    }
    tot[t] = run;                          // total nodes in bin t
    __syncthreads();
    // ioff[b] = sum_{b' > b} tot[b']  (largest-degree bin first)
    int v2 = tot[255 - t];
    s[t] = v2; __syncthreads();
    for (int d = 1; d < 256; d <<= 1) {
        int u = (t >= d) ? s[t - d] : 0;
        __syncthreads();
        s[t] += u;
        __syncthreads();
    }
    ioff[255 - t] = s[t] - v2;
}

// finalize csr; emit perm (degree-sorted descending); fill pad slots
__global__ void scan3_kernel(int* __restrict__ csr, const int* __restrict__ boff,
                             const int* __restrict__ deg, const int* __restrict__ rankN,
                             const int* __restrict__ ioff, const int* __restrict__ bhist,
                             int* __restrict__ perm,
                             int* __restrict__ srcS, unsigned int* __restrict__ eaS) {
    int n = blockIdx.x * 256 + threadIdx.x;
    int base = csr[n] + boff[blockIdx.x];
    csr[n] = base;
    if (n < NN) {
        int d = deg[n];
        int dp = (d + 3) & ~3;
        int b = dp >> 2; if (b > 255) b = 255;
        perm[ioff[b] + bhist[b * 196 + blockIdx.x] + rankN[n]] = n;
        for (int k = d; k < dp; k++) {
            srcS[base + k] = NN;
            uint2 z2 = {0u, 0u};          // bf16 zeros
            *(uint2*)&eaS[(size_t)(base + k) * 2] = z2;
        }
    }
}

// one pass: place each edge's src + edge_attr(bf16x4, 8B) at its padded-CSR
// slot. pos = csr[dst] + replica offset + local rank.
__global__ void scatter_gather_kernel(const int* __restrict__ dst, const int* __restrict__ src,
                                      const int* __restrict__ rank, const int* __restrict__ csr,
                                      const int* __restrict__ deg8,
                                      const float* __restrict__ ea,
                                      int* __restrict__ srcS, unsigned int* __restrict__ eaS) {
    int e = blockIdx.x * 256 + threadIdx.x;
    if (e < NE) {
        int rk  = rank[e];
        int rep = rk & 7;
        int d   = dst[e];
        int pos = csr[d] + deg8[rep * 50176 + d] + (rk >> 3);
        srcS[pos] = src[e];
        float4 v = *(const float4*)&ea[(size_t)e * 4];
        uint2 p;
        p.x = (unsigned int)f2bf(v.x) | ((unsigned int)f2bf(v.y) << 16);
        p.y = (unsigned int)f2bf(v.z) | ((unsigned int)f2bf(v.w) << 16);
        *(uint2*)&eaS[(size_t)pos * 2] = p;
    }
}

// ---------------------------------------------------------------------------
// Aggregation (best-known round-2 structure): 4 nodes/wave (16 lanes/node,
// 8 ch/lane), uniform 4-batches (CSR padded), degree-sorted perm, 2-stage
// software pipeline. eaS is bf16x4 (8B/edge), unpacked in VALU (headroom).
// Deeper pipelining (3-slot, 136 VGPR) measured WORSE (occ 9%); channel
// split measured neutral-worse. ~100MB FETCH / ~39us = random-gather floor.
// ---------------------------------------------------------------------------
__global__ __launch_bounds__(256) void agg_kernel(
    const ushort* __restrict__ zy, const unsigned int* __restrict__ eaS,
    const float* __restrict__ W3,
    const int* __restrict__ srcS, const int* __restrict__ csr,
    const int* __restrict__ perm,
    ushort* __restrict__ xh,
    const float* __restrict__ Wo, const float* __restrict__ bo,
    float* __restrict__ outp, int lastLayer)
{
    const int wv   = (blockIdx.x * 256 + threadIdx.x) >> 6;  // 0..12499
    const int lane = threadIdx.x & 63;
    const int g    = lane >> 4;          // node group 0..3
    const int li   = lane & 15;
    const int n    = perm[wv * 4 + g];   // degree-sorted node id
    const int c0   = li * 8;             // channel base

    f32x2 w[4][4];
#pragma unroll
    for (int d = 0; d < 4; d++)
#pragma unroll
        for (int q2 = 0; q2 < 4; q2++) {
            float2 t = *(const float2*)&W3[d * HIDD + c0 + 2 * q2];
            w[d][q2] = {t.x, t.y};
        }

    uint4 yu = *(const uint4*)&zy[(size_t)n * 256 + 128 + c0];
    f32x2 y2[4] = {{lo16f(yu.x), hi16f(yu.x)}, {lo16f(yu.y), hi16f(yu.y)},
                   {lo16f(yu.z), hi16f(yu.z)}, {lo16f(yu.w), hi16f(yu.w)}};

    size_t xi = (size_t)n * HIDD + c0;
    uint4 uh = *(const uint4*)&xh[xi];
    f32x2 acc[4] = {{lo16f(uh.x), hi16f(uh.x)},
                    {lo16f(uh.y), hi16f(uh.y)},
                    {lo16f(uh.z), hi16f(uh.z)},
                    {lo16f(uh.w), hi16f(uh.w)}};

    int i   = csr[n];
    int end = csr[n + 1];
    int nb  = (end - i) >> 2;
    int iLast = end - 4;

#define ZLD(sidx) (*(const uint4*)&zy[((size_t)(unsigned)(sidx)) * 256 + c0])
#define ALD(p)    (*(const uint2*)&eaS[(size_t)(p) * 2])
#define EDGE(zk, ak) do {                                                   \
        const unsigned int zc_[4] = {(zk).x, (zk).y, (zk).z, (zk).w};       \
        float ax_ = lo16f((ak).x), ay_ = hi16f((ak).x);                     \
        float az_ = lo16f((ak).y), aw_ = hi16f((ak).y);                     \
        _Pragma("unroll")                                                   \
        for (int q2 = 0; q2 < 4; q2++) {                                    \
            f32x2 m = {lo16f(zc_[q2]), hi16f(zc_[q2])};                     \
            m += y2[q2];                                                    \
            m += ax_ * w[0][q2];                                            \
            m += ay_ * w[1][q2];                                            \
            m += az_ * w[2][q2];                                            \
            m += aw_ * w[3][q2];                                            \
            acc[q2].x += fmaxf(m.x, 0.f);                                   \
            acc[q2].y += fmaxf(m.y, 0.f);                                   \
        }                                                                   \
    } while (0)

    uint4 z0, z1, z2, z3;
    uint2 a0, a1, a2, a3;
    int4 sn;
    if (nb > 0) {
        int4 sc = *(const int4*)&srcS[i];
        int i1 = (i + 4 <= iLast) ? i + 4 : iLast;
        sn = *(const int4*)&srcS[i1];
        z0 = ZLD(sc.x); z1 = ZLD(sc.y); z2 = ZLD(sc.z); z3 = ZLD(sc.w);
        a0 = ALD(i); a1 = ALD(i + 1); a2 = ALD(i + 2); a3 = ALD(i + 3);
    }
    for (int k = 0; k < nb; k++) {
        int inext = (i + 4 <= iLast) ? i + 4 : iLast;   // batch k+1 (clamped)
        int inn   = (i + 8 <= iLast) ? i + 8 : iLast;   // batch k+2 (clamped)
        // issue next batch's gathers BEFORE consuming current batch
        uint4 n0 = ZLD(sn.x), n1 = ZLD(sn.y), n2 = ZLD(sn.z), n3 = ZLD(sn.w);
        uint2 b0 = ALD(inext), b1 = ALD(inext + 1), b2 = ALD(inext + 2), b3 = ALD(inext + 3);
        int4 snn = *(const int4*)&srcS[inn];
        // consume current batch (loads already in flight since last iter)
        EDGE(z0, a0); EDGE(z1, a1); EDGE(z2, a2); EDGE(z3, a3);
        z0 = n0; z1 = n1; z2 = n2; z3 = n3;
        a0 = b0; a1 = b1; a2 = b2; a3 = b3;
        sn = snn;
        i += 4;
    }
#undef ZLD
#undef ALD
#undef EDGE

    if (!lastLayer) {
        uint4 oh;
        unsigned int* ph = &oh.x;
#pragma unroll
        for (int q2 = 0; q2 < 4; q2++) {
            ushort h0 = f2bf(acc[q2].x), h1 = f2bf(acc[q2].y);
            ph[q2] = (unsigned int)h0 | ((unsigned int)h1 << 16);
        }
        *(uint4*)&xh[xi] = oh;
    } else {
        float p0 = 0.f, p1 = 0.f, p2 = 0.f;
#pragma unroll
        for (int q = 0; q < 8; q++) {
            float xv = (q & 1) ? acc[q >> 1].y : acc[q >> 1].x;
            int ch = c0 + q;
            p0 += xv * Wo[ch * ODIM + 0];
            p1 += xv * Wo[ch * ODIM + 1];
            p2 += xv * Wo[ch * ODIM + 2];
        }
#pragma unroll
        for (int off = 1; off < 16; off <<= 1) {
            p0 += __shfl_xor(p0, off);
            p1 += __shfl_xor(p1, off);
            p2 += __shfl_xor(p2, off);
        }
        if (li == 0) {
            outp[(size_t)n * ODIM + 0] = p0 + bo[0];
            outp[(size_t)n * ODIM + 1] = p1 + bo[1];
            outp[(size_t)n * ODIM + 2] = p2 + bo[2];
        }
    }
}

// ---------------------------------------------------------------------------
extern "C" void kernel_launch(void* const* d_in, const int* in_sizes, int n_in,
                              void* d_out, int out_size, void* d_ws, size_t ws_size,
                              hipStream_t stream)
{
    const float* h     = (const float*)d_in[0];
    const int*   ei    = (const int*)  d_in[1];
    const float* ea    = (const float*)d_in[2];
    const float* W_in  = (const float*)d_in[3];
    const float* b_in  = (const float*)d_in[4];
    const float* W_msg = (const float*)d_in[5];
    const float* b_msg = (const float*)d_in[6];
    const float* W_out = (const float*)d_in[7];
    const float* b_out = (const float*)d_in[8];
    float* out = (float*)d_out;

    // workspace carve-up (~60 MB); EP (padded edges) <= NE + 3*NN = 950000
    ushort* zy     = (ushort*)d_ws;                        // 50001*256 us
    ushort* xh     = zy + 12800256;                        // 6.4M us
    ushort* winTh  = xh + 6400000;                         // 32768
    ushort* winTl  = winTh + 32768;                        // 32768
    ushort* wzyTh  = winTl + 32768;                        // 131072
    ushort* wzyTl  = wzyTh + 131072;                       // 131072
    float*  bias256= (float*)(wzyTl + 131072);             // 1024 f
    unsigned int* eaS = (unsigned int*)(bias256 + 1024);   // 1.9M u32 (bf16x4/edge)
    int*    srcS   = (int*)(eaS + 1900000);                // 950k
    int*    rank   = srcS + 950000;                        // 800k
    int*    deg    = rank + 800000;                        // 50176
    int*    deg8   = deg + 50176;                          // 8*50176 = 401408
    int*    csr    = deg8 + 401408;                        // 50176
    int*    bsum   = csr + 50176;                          // 256
    int*    boff   = bsum + 256;                           // 256
    int*    ioff   = boff + 256;                           // 256
    int*    rankN  = ioff + 256;                           // 50176
    int*    perm   = rankN + 50176;                        // 50176
    int*    bhist  = perm + 50176;                         // 50176 (bin-major)

    const int* srcA = ei;        // edge_index[0]
    const int* dstA = ei + NE;   // edge_index[1]

    // allow >64KB dynamic LDS (in-proj 67.6 KB, zy GEMM 69.6 KB)
    hipFuncSetAttribute((const void*)&gemm_wres_f32<4, 8>,
                        hipFuncAttributeMaxDynamicSharedMemorySize, 2 * 64 * 264 * 2);
    hipFuncSetAttribute((const void*)&gemm_wres<8, 4>,
                        hipFuncAttributeMaxDynamicSharedMemorySize, 2 * 128 * 136 * 2);

    // weight prep (merged) + dummy zy row + deg8 zeroing (memset folded in)
    conv_weights<<<1568, 256, 0, stream>>>(W_in, W_msg, b_msg,
                                           winTh, winTl, wzyTh, wzyTl, bias256, zy, deg8);

    // padded CSR build + degree-sort perm (replicated histogram, two-level sort)
    histrank_kernel<<<3125, 256, 0, stream>>>(dstA, deg8, rank);
    scan1_kernel<<<196, 256, 0, stream>>>(deg8, deg, csr, bsum, bhist, rankN);
    scan2_kernel<<<1, 256, 0, stream>>>(bsum, boff, bhist, ioff);
    scan3_kernel<<<196, 256, 0, stream>>>(csr, boff, deg, rankN, ioff, bhist, perm, srcS, eaS);
    scatter_gather_kernel<<<3125, 256, 0, stream>>>(dstA, srcA, rank, csr, deg8, ea, srcS, eaS);

    // input projection straight from fp32 h (exact 3-term in-register split)
    gemm_wres_f32<4, 8><<<400, 512, 2 * 64 * 264 * 2, stream>>>(
        h, winTh, winTl, b_in, xh, NN, INDIM, HIDD);

    for (int l = 0; l < NLAYERS; l++) {
        // zy = x @ [W1|W2] + bias, 2-term (A bf16, weight hi/lo), NJ=8
        gemm_wres<8, 4><<<400, 512, 2 * 128 * 136 * 2, stream>>>(
            xh, wzyTh + (size_t)l * 32768, wzyTl + (size_t)l * 32768,
            bias256 + l * 256, zy, NN, HIDD, 256);
        agg_kernel<<<3125, 256, 0, stream>>>(
            zy, eaS, W_msg + (size_t)l * 33280 + 256 * 128,
            srcS, csr, perm, xh, W_out, b_out, out,
            (l == NLAYERS - 1) ? 1 : 0);
    }
}